// Round 4
// baseline (1262.035 us; speedup 1.0000x reference)
//
#include <hip/hip_runtime.h>

#define CODES_ELEMS 8388608   // 16*1024*512
#define N_ROWS      131072    // 16*1024*8
#define IDX_OFF     CODES_ELEMS
#define LOSS_OFF    (CODES_ELEMS + N_ROWS)

// d_ws: [0,4) int dtype flag (1 = bf16), [4,8) float loss acc, [64,8256) cc[2048]
__device__ __forceinline__ float bf2f(unsigned short h) {
  return __uint_as_float(((unsigned)h) << 16);
}
__device__ __forceinline__ unsigned short f2bf(float f) {  // round-nearest-even
  unsigned u = __float_as_uint(f);
  u += 0x7fffu + ((u >> 16) & 1u);
  return (unsigned short)(u >> 16);
}

// Runtime dtype sniff: in bf16 data the low 16 bits of each u32 hold a full
// bf16 (exp field ~[100,132] for N(0,1) w.p. ~0.999); in fp32 data those bits
// are uniform mantissa bits (in-range w.p. ~0.13). Ballot-count 64 samples.
__global__ void vq_sniff(const unsigned* z32, int* flag, float* loss_acc) {
  int t = threadIdx.x;                       // 64 threads
  unsigned u = z32[t];
  int v = (int)((u >> 7) & 0xFF);
  unsigned long long m = __ballot(v >= 100 && v <= 132);
  if (t == 0) {
    flag[0] = (__popcll(m) >= 32) ? 1 : 0;
    loss_acc[0] = 0.f;
  }
}

// cc[k] = sum_d codebook[k][d]^2 in fp32 (one wave per code, lane = dim)
__global__ __launch_bounds__(256) void vq_prep(const float* cf, const unsigned short* ch,
                                               const int* flag, float* cc) {
  int e = blockIdx.x * 256 + threadIdx.x;    // 512*256 = 2048 codes * 64 dims
  float v = flag[0] ? bf2f(ch[e]) : cf[e];
  float s = v * v;
  #pragma unroll
  for (int m = 1; m < 64; m <<= 1) s += __shfl_xor(s, m, 64);
  if ((threadIdx.x & 63) == 0) cc[e >> 6] = s;
}

// Block = 64 z-rows x all 2048 codes, 256 threads, 4x4 register tile per thread.
// dist = fl(zz - 2*dot) + cc  (matches np's expression; 2*dot is exact).
__global__ __launch_bounds__(256) void VQQuantizer_30064771072206_kernel(
    const float* zf, const unsigned short* zh,
    const float* cf, const unsigned short* ch,
    const float* cc, const int* flag, float* loss_acc, void* outv)
{
  __shared__ __align__(16) float zt[64][68];   // [d][row], +4 pad: hot reads 2-way (free)
  __shared__ __align__(16) float ct[64][68];   // [d][code]
  __shared__ float zz_l[64];
  __shared__ float cc_l[64];
  __shared__ int   idxbuf[64];
  __shared__ float wsum[4];
  const int t  = threadIdx.x;
  const int tx = t & 15, ty = t >> 4;          // tx -> code quad, ty -> row quad
  const int rowbase = blockIdx.x * 64;
  const int bf = flag[0];

  // stage z transposed: 64 rows x 64 dims, coalesced global reads
  #pragma unroll
  for (int i = 0; i < 16; ++i) {
    int e = t + i * 256;
    int row = e >> 6, d = e & 63;
    int g = (rowbase + row) * 64 + d;
    zt[d][row] = bf ? bf2f(zh[g]) : zf[g];
  }
  __syncthreads();
  if (t < 64) {
    float s = 0.f;
    for (int d = 0; d < 64; ++d) s += zt[d][t] * zt[d][t];
    zz_l[t] = s;
  }
  __syncthreads();
  float zz_r[4];
  #pragma unroll
  for (int i = 0; i < 4; ++i) zz_r[i] = zz_l[ty * 4 + i];

  float bestv[4] = {3.402823466e38f, 3.402823466e38f, 3.402823466e38f, 3.402823466e38f};
  int   besti[4] = {0, 0, 0, 0};

  for (int chunk = 0; chunk < 32; ++chunk) {
    __syncthreads();                           // prior ct fully consumed
    #pragma unroll
    for (int i = 0; i < 16; ++i) {             // stage 64-code chunk, transposed
      int e = t + i * 256;
      int code = e >> 6, d = e & 63;
      int g = (chunk * 64 + code) * 64 + d;
      ct[d][code] = bf ? bf2f(ch[g]) : cf[g];
    }
    if (t < 64) cc_l[t] = cc[chunk * 64 + t];
    __syncthreads();

    float acc[4][4];
    #pragma unroll
    for (int i = 0; i < 4; ++i)
      #pragma unroll
      for (int j = 0; j < 4; ++j) acc[i][j] = 0.f;

    #pragma unroll 8
    for (int d = 0; d < 64; ++d) {
      float4 zv = *(const float4*)&zt[d][ty * 4];
      float4 cv = *(const float4*)&ct[d][tx * 4];
      acc[0][0] += zv.x * cv.x; acc[0][1] += zv.x * cv.y; acc[0][2] += zv.x * cv.z; acc[0][3] += zv.x * cv.w;
      acc[1][0] += zv.y * cv.x; acc[1][1] += zv.y * cv.y; acc[1][2] += zv.y * cv.z; acc[1][3] += zv.y * cv.w;
      acc[2][0] += zv.z * cv.x; acc[2][1] += zv.z * cv.y; acc[2][2] += zv.z * cv.z; acc[2][3] += zv.z * cv.w;
      acc[3][0] += zv.w * cv.x; acc[3][1] += zv.w * cv.y; acc[3][2] += zv.w * cv.z; acc[3][3] += zv.w * cv.w;
    }
    #pragma unroll
    for (int j = 0; j < 4; ++j) {              // ascending code order: np first-wins ties
      int code = chunk * 64 + tx * 4 + j;
      float ccv = cc_l[tx * 4 + j];
      #pragma unroll
      for (int i = 0; i < 4; ++i) {
        float t1 = zz_r[i] - 2.0f * acc[i][j]; // 2*acc exact -> same rounding as np
        float dist = t1 + ccv;
        if (dist < bestv[i]) { bestv[i] = dist; besti[i] = code; }
      }
    }
  }

  // merge across the 16 threads (consecutive lanes) sharing a row quad
  #pragma unroll
  for (int i = 0; i < 4; ++i) {
    float v = bestv[i]; int idx = besti[i];
    #pragma unroll
    for (int m = 1; m < 16; m <<= 1) {
      float ov = __shfl_xor(v, m, 64);
      int   oi = __shfl_xor(idx, m, 64);
      if (ov < v || (ov == v && oi < idx)) { v = ov; idx = oi; }
    }
    if (tx == 0) idxbuf[ty * 4 + i] = idx;
  }
  __syncthreads();

  if (t < 64) {
    if (bf) ((unsigned short*)outv)[IDX_OFF + rowbase + t] = f2bf((float)idxbuf[t]);
    else    ((float*)outv)[IDX_OFF + rowbase + t] = (float)idxbuf[t];
  }

  // codes = zg + (zq - zg) (straight-through), commit loss in fp32
  float lsum = 0.f;
  #pragma unroll
  for (int i = 0; i < 16; ++i) {
    int e = t + i * 256;
    int row = e >> 6, d = e & 63;
    int g = (rowbase + row) * 64 + d;
    int k = idxbuf[row];                       // wave-uniform -> broadcast load
    float zq = bf ? bf2f(ch[k * 64 + d]) : cf[k * 64 + d];
    float zg = bf ? bf2f(zh[g]) : zf[g];
    float di = zq - zg;
    float st = zg + di;
    if (bf) ((unsigned short*)outv)[g] = f2bf(st);
    else    ((float*)outv)[g] = st;
    lsum += di * di;
  }
  #pragma unroll
  for (int m = 1; m < 64; m <<= 1) lsum += __shfl_xor(lsum, m, 64);
  if ((t & 63) == 0) wsum[t >> 6] = lsum;
  __syncthreads();
  if (t == 0) atomicAdd(loss_acc, wsum[0] + wsum[1] + wsum[2] + wsum[3]);
}

__global__ void vq_finalize(const float* loss_acc, const int* flag, void* outv) {
  float v = loss_acc[0] * (1.f / 8388608.f);
  if (flag[0]) ((unsigned short*)outv)[LOSS_OFF] = f2bf(v);
  else         ((float*)outv)[LOSS_OFF] = v;
}

extern "C" void kernel_launch(void* const* d_in, const int* in_sizes, int n_in,
                              void* d_out, int out_size, void* d_ws, size_t ws_size,
                              hipStream_t stream) {
  const float*          zf = (const float*)d_in[0];
  const unsigned short* zh = (const unsigned short*)d_in[0];
  const float*          cf = (const float*)d_in[1];
  const unsigned short* ch = (const unsigned short*)d_in[1];
  int*   flag     = (int*)d_ws;
  float* loss_acc = (float*)((char*)d_ws + 4);
  float* cc       = (float*)((char*)d_ws + 64);

  vq_sniff<<<1, 64, 0, stream>>>((const unsigned*)d_in[0], flag, loss_acc);
  vq_prep<<<512, 256, 0, stream>>>(cf, ch, flag, cc);
  VQQuantizer_30064771072206_kernel<<<2048, 256, 0, stream>>>(
      zf, zh, cf, ch, cc, flag, loss_acc, d_out);
  vq_finalize<<<1, 1, 0, stream>>>(loss_acc, flag, d_out);
}